// Round 1
// 73.517 us; speedup vs baseline: 1.0000x; 1.0000x over previous
//
#include <hip/hip_runtime.h>

// B=8, N=512, D=64, E=32
// ws layout (in _Float16 units):
//   src = hws[0 .. BNE)          (4096 rows x 32)
//   dst = hws[BNE .. 2*BNE)
//   WrH = hws[2*BNE .. 2*BNE+16384)   (Wr converted to f16)
#define BNE (4096 * 32)

typedef _Float16 h1;
typedef __attribute__((ext_vector_type(2))) _Float16 h2;

// Kernel 1: src/dst projections -> f16 ws. 4 rows per block (one per wave),
// x staged through LDS with one coalesced load. Folds be into src.
// Blocks 0..15 additionally convert Wr -> f16 and init out = br.
__global__ __launch_bounds__(256) void proj_kernel(
    const float* __restrict__ x, const float* __restrict__ We,
    const float* __restrict__ be, const float* __restrict__ Wr,
    const float* __restrict__ br,
    float* __restrict__ out, h1* __restrict__ hws)
{
    __shared__ float xs[4][64];
    const int t  = threadIdx.x;          // 0..255
    const int r0 = blockIdx.x << 2;      // 4 rows per block

    xs[t >> 6][t & 63] = x[(size_t)r0 * 64 + t];   // coalesced 1 KB/block
    __syncthreads();

    const int w    = t >> 6;             // wave id = row sub-index
    const int lane = t & 63;
    const int proj = lane >> 5;          // 0 = src, 1 = dst
    const int e    = lane & 31;

    const float* __restrict__ wcol = We + proj * (64 * 32) + e;  // coalesced
    float acc = 0.0f;
    #pragma unroll
    for (int d = 0; d < 64; ++d)
        acc = fmaf(xs[w][d], wcol[d * 32], acc);   // xs read = wave broadcast
    if (proj == 0) acc += be[e];

    hws[(size_t)proj * BNE + (size_t)(r0 + w) * 32 + e] = (h1)acc;

    if (blockIdx.x < 16) {
        const int idx = (blockIdx.x << 8) + t;     // 0..4095
        out[idx] = br[0];
        const float4 wv = ((const float4*)Wr)[idx];
        h1* __restrict__ wh = hws + 2 * (size_t)BNE + (size_t)idx * 4;
        wh[0] = (h1)wv.x; wh[1] = (h1)wv.y; wh[2] = (h1)wv.z; wh[3] = (h1)wv.w;
    }
}

// Kernel 2: delta[b,j] += sum_{i,e} relu(src[b,i,e]+dst[b,j,e]) * Wr[i*32+e].
// f16 packed math (v_pk_add_f16 + v_pk_max_f16 = 2 edges/instr), f32
// accumulation via v_fma_mix_f32 (f16 sources). One j per thread, i-tile=16,
// grid (32,1,8) = 256 blocks x 8 waves = 1 block/CU, 2 waves/SIMD.
// src/Wr rows are wave-uniform -> scalar-load path. Atomics: 1/thread.
__global__ __launch_bounds__(512) void edge_kernel(
    const h1* __restrict__ hws, float* __restrict__ out)
{
    const h1* __restrict__ src = hws;
    const h1* __restrict__ dst = hws + BNE;
    const h1* __restrict__ wr  = hws + 2 * (size_t)BNE;

    const int b  = blockIdx.z;
    const int j  = threadIdx.x;          // 0..511
    const int i0 = blockIdx.x << 4;      // i-tile of 16

    union { float4 f4[4]; h2 d[16]; } u;
    const float4* __restrict__ dp =
        (const float4*)(dst + ((size_t)(b * 512 + j)) * 32);
    #pragma unroll
    for (int k = 0; k < 4; ++k) u.f4[k] = dp[k];   // 64 B dst row

    const h2 hzero = { (h1)0, (h1)0 };
    float a0 = 0.f, a1 = 0.f, a2 = 0.f, a3 = 0.f;

    #pragma unroll 4
    for (int ii = 0; ii < 16; ++ii) {
        const int i = i0 + ii;
        const h2* __restrict__ srow =
            (const h2*)(src + ((size_t)(b * 512 + i)) * 32);   // uniform
        const h2* __restrict__ wrow =
            (const h2*)(wr + (size_t)i * 32);                  // uniform
        #pragma unroll
        for (int e2 = 0; e2 < 16; ++e2) {
            const h2 s  = srow[e2];
            const h2 wv = wrow[e2];
            const h2 tt = __builtin_elementwise_max(s + u.d[e2], hzero);
            if (e2 & 1) {
                a2 = fmaf((float)tt.x, (float)wv.x, a2);   // v_fma_mix_f32
                a3 = fmaf((float)tt.y, (float)wv.y, a3);
            } else {
                a0 = fmaf((float)tt.x, (float)wv.x, a0);
                a1 = fmaf((float)tt.y, (float)wv.y, a1);
            }
        }
    }
    atomicAdd(&out[b * 512 + j], (a0 + a1) + (a2 + a3));
}

extern "C" void kernel_launch(void* const* d_in, const int* in_sizes, int n_in,
                              void* d_out, int out_size, void* d_ws, size_t ws_size,
                              hipStream_t stream) {
    const float* x  = (const float*)d_in[0];   // (8,512,64)
    const float* We = (const float*)d_in[1];   // (128,32)
    const float* be = (const float*)d_in[2];   // (32,)
    const float* Wr = (const float*)d_in[3];   // (16384,1)
    const float* br = (const float*)d_in[4];   // (1,)
    float* out = (float*)d_out;                // (8,512,1) = 4096 floats
    h1* hws = (h1*)d_ws;

    proj_kernel<<<1024, 256, 0, stream>>>(x, We, be, Wr, br, out, hws);
    edge_kernel<<<dim3(32, 1, 8), 512, 0, stream>>>(hws, out);
}